// Round 6
// baseline (18570.206 us; speedup 1.0000x reference)
//
#include <hip/hip_runtime.h>

// LSTM: VOCAB=50000, EMBED=50, NFEAT=3, T=120, HIDDEN=300, NCLASS=5, BATCH=1024
// R6: XCD-local h exchange. 256 blocks @ 1 block/CU (LDS-forced) => exactly
// 32 blocks per XCD. Each block reads HW_REG_XCC_ID and takes a rank; XCD x
// serves bgs 4x..4x+3 (GH=5 slices each), ranks>=20 exit. All h/flag traffic
// stays in the XCD's L2: plain write-through stores + vmcnt(0), L2-point
// atomic flag add (no sc bits), sc0 poll loads, buffer_inv (L1) per step.

#define BATCH 1024
#define TT    120
#define HID   300
#define KX    160   // padded K for x (150 -> 160)
#define KH    320   // padded K for h: 5 slices * 64
#define SL    64    // padded units per slice
#define HSL   60    // valid units per slice
#define NCOL  1280  // 5 slices * 256 packed gate columns
#define GH    5     // hidden slices
#define GB    32    // batch groups
#define BS    32    // batch rows per group
#define XST   168   // x_lds row stride in shorts (336B)
#define FSTR  32    // flag stride in ints (128B)
#define NSLOT 3
#define NB    256   // blocks launched (1 per CU)

typedef __attribute__((ext_vector_type(8))) short bf16x8;
typedef __attribute__((ext_vector_type(4))) float f32x4;

__device__ __forceinline__ unsigned short f2b(float f) {
  union { float f; unsigned u; } v; v.f = f;
  unsigned r = v.u + 0x7fffu + ((v.u >> 16) & 1u);
  return (unsigned short)(r >> 16);
}
__device__ __forceinline__ float sigm(float x) {
  return __builtin_amdgcn_rcpf(1.f + __expf(-x));
}
__device__ __forceinline__ float tanhf_(float x) {
  return 2.f * __builtin_amdgcn_rcpf(1.f + __expf(-2.f * x)) - 1.f;
}
// L2-direct 4B load (bypasses L1; meets L2-point atomics where they land)
__device__ __forceinline__ int l2_load(const int* p) {
  int v;
  asm volatile("global_load_dword %0, %1, off sc0\n\ts_waitcnt vmcnt(0)"
               : "=v"(v) : "v"(p) : "memory");
  return v;
}
// L2-point atomic add, no return, no sc bits (stays in this XCD's L2)
__device__ __forceinline__ void l2_atomic_add(int* p, int v) {
  asm volatile("global_atomic_add %0, %1, off" :: "v"(p), "v"(v) : "memory");
}

// column map: c in [0,1280): j=c>>8, r=c&255, g=r>>6, u0=r&63; valid u0<60
__global__ void k_reorder_wh(const float* __restrict__ W, unsigned short* __restrict__ Wp) {
  int tid = blockIdx.x * 256 + threadIdx.x;
  if (tid >= KH * NCOL) return;
  int c = tid % NCOL, k = tid / NCOL;
  int js = k >> 6, v0 = k & 63;
  int j = c >> 8, r = c & 255, g = r >> 6, u0 = r & 63;
  float val = 0.f;
  if (v0 < HSL && u0 < HSL) val = W[(js * HSL + v0) * 1200 + g * 300 + j * HSL + u0];
  Wp[((k >> 3) * NCOL + c) * 8 + (k & 7)] = f2b(val);
}

__global__ void k_reorder_wx(const float* __restrict__ W, unsigned short* __restrict__ Wp) {
  int tid = blockIdx.x * 256 + threadIdx.x;
  if (tid >= KX * NCOL) return;
  int c = tid % NCOL, k = tid / NCOL;
  int j = c >> 8, r = c & 255, g = r >> 6, u0 = r & 63;
  float val = 0.f;
  if (k < 150 && u0 < HSL) val = W[k * 1200 + g * 300 + j * HSL + u0];
  Wp[((k >> 3) * NCOL + c) * 8 + (k & 7)] = f2b(val);
}

__global__ void k_reorder_b(const float* __restrict__ b, float* __restrict__ bp) {
  int c = blockIdx.x * 256 + threadIdx.x;
  if (c >= NCOL) return;
  int j = c >> 8, r = c & 255, g = r >> 6, u0 = r & 63;
  bp[c] = (u0 < HSL) ? b[g * 300 + j * HSL + u0] : 0.f;
}

__global__ void k_reorder_u(const float* __restrict__ U, unsigned short* __restrict__ Up) {
  int tid = blockIdx.x * 256 + threadIdx.x;
  if (tid >= KH * 16) return;
  int n = tid % 16, k = tid / 16;
  int js = k >> 6, v0 = k & 63;
  float v = (v0 < HSL && n < 5) ? U[(js * HSL + v0) * 5 + n] : 0.f;
  Up[((k >> 3) * 16 + n) * 8 + (k & 7)] = f2b(v);
}

__launch_bounds__(256, 1)
__global__ void k_lstm(const int* __restrict__ ids, const float* __restrict__ embed,
                       const unsigned short* __restrict__ Wp,
                       const unsigned short* __restrict__ Wxp,
                       const float* __restrict__ bp,
                       const unsigned short* __restrict__ Up,
                       unsigned short* __restrict__ hbuf,   // [3][1024][320] bf16
                       int* __restrict__ flags,             // [120][32] @128B
                       int* __restrict__ xcd_cnt,           // [8]
                       const float* __restrict__ b2,
                       float* __restrict__ out) {
  __shared__ __align__(16) unsigned short x_lds[2][BS * XST];
  __shared__ char lds_pad[61440];   // force 1 block/CU (total LDS > 80KB)
  __shared__ int role[2];

  const int tid = threadIdx.x;
  if (tid == 0) {
    ((volatile char*)lds_pad)[0] = 0;  // keep pad allocated
    int xcd = __builtin_amdgcn_s_getreg(63508) & 7;  // HW_REG_XCC_ID (id20,sz32)
    int rank = atomicAdd(&xcd_cnt[xcd], 1);
    role[0] = xcd; role[1] = rank;
  }
  __syncthreads();
  const int xcd = role[0], rank = role[1];
  if (rank >= GH * 4) return;               // spare block
  const int bg = xcd * 4 + rank / GH;       // 8 XCDs x 4 bgs = 32
  const int j  = rank % GH;

  const int lane = tid & 63, w = tid >> 6;  // 4 waves; wave w owns units w*16..+15
  const int l15 = lane & 15, l4 = lane >> 4;

  if (tid < BS) {
#pragma unroll
    for (int bq = 0; bq < 2; ++bq)
      for (int e = 150; e < XST; ++e) x_lds[bq][tid * XST + e] = 0;
  }

  const int colb = j * 256 + w * 16 + l15;

  // persistent B fragments (linear k-pack: elem e of k-row (kk*4+l4) is k=kk*32+l4*8+e)
  bf16x8 bh[10][4], bx[5][4], up[10];
#pragma unroll
  for (int kk = 0; kk < 10; ++kk)
#pragma unroll
    for (int g = 0; g < 4; ++g)
      bh[kk][g] = *(const bf16x8*)(Wp + ((kk * 4 + l4) * NCOL + colb + g * 64) * 8);
#pragma unroll
  for (int kk = 0; kk < 5; ++kk)
#pragma unroll
    for (int g = 0; g < 4; ++g)
      bx[kk][g] = *(const bf16x8*)(Wxp + ((kk * 4 + l4) * NCOL + colb + g * 64) * 8);
#pragma unroll
  for (int kk = 0; kk < 10; ++kk)
    up[kk] = *(const bf16x8*)(Up + ((kk * 4 + l4) * 16 + l15) * 8);

  float bias[4];
#pragma unroll
  for (int g = 0; g < 4; ++g) bias[g] = bp[colb + g * 64];
  const float b2v = (l15 < 5) ? b2[l15] : 0.f;

  // ---- x(0) gather: 192 threads = 32 rows x 3 feats x 2 halves (26/24 split)
  if (tid < 192) {
    int xrow = tid / 6, half = tid % 6, f = half >> 1, hh = half & 1;
    int nf2 = hh ? 12 : 13;
    int koff = f * 50 + (hh ? 26 : 0);
    int id = ids[((bg * BS + xrow) * TT + 0) * 3 + f];
    const float* src = embed + (long)id * 50 + (hh ? 26 : 0);
    unsigned short* dst = &x_lds[0][xrow * XST + koff];
#pragma unroll
    for (int e = 0; e < 13; ++e)
      if (e < nf2) {
        float2 v = *(const float2*)(src + 2 * e);
        *(unsigned*)(dst + 2 * e) = (unsigned)f2b(v.x) | ((unsigned)f2b(v.y) << 16);
      }
  }
  __syncthreads();

  f32x4 acc[4][2];
  float cst[2][4];
#pragma unroll
  for (int g = 0; g < 4; ++g)
#pragma unroll
    for (int mt = 0; mt < 2; ++mt) acc[g][mt] = {0.f, 0.f, 0.f, 0.f};
#pragma unroll
  for (int mt = 0; mt < 2; ++mt)
#pragma unroll
    for (int r = 0; r < 4; ++r) cst[mt][r] = 0.f;

  // GEMM1(0)
  {
    const unsigned short* xb = &x_lds[0][l15 * XST + l4 * 8];
#pragma unroll
    for (int kk = 0; kk < 5; ++kk) {
      bf16x8 a0 = *(const bf16x8*)(xb + kk * 32);
      bf16x8 a1 = *(const bf16x8*)(xb + 16 * XST + kk * 32);
#pragma unroll
      for (int g = 0; g < 4; ++g) {
        acc[g][0] = __builtin_amdgcn_mfma_f32_16x16x32_bf16(a0, bx[kk][g], acc[g][0], 0, 0, 0);
        acc[g][1] = __builtin_amdgcn_mfma_f32_16x16x32_bf16(a1, bx[kk][g], acc[g][1], 0, 0, 0);
      }
    }
  }

  for (int t = 0; t < TT; ++t) {
    // issue x(t+1) loads first (read-only data; unaffected by cache inv)
    float2 xv[13];
    int xrow = 0, koff = 0, nf2 = 0;
    const bool xact = (t + 1 < TT) && (tid < 192);
    if (xact) {
      xrow = tid / 6; int half = tid % 6, f = half >> 1, hh = half & 1;
      nf2 = hh ? 12 : 13;
      koff = f * 50 + (hh ? 26 : 0);
      int id = ids[((bg * BS + xrow) * TT + (t + 1)) * 3 + f];
      const float* src = embed + (long)id * 50 + (hh ? 26 : 0);
#pragma unroll
      for (int e = 0; e < 13; ++e)
        if (e < nf2) xv[e] = *(const float2*)(src + 2 * e);
    }

    if (t > 0) {
      if (tid == 0) {  // sc0 poll: reads the XCD L2 where partners' adds land
        int* fp = flags + ((t - 1) * GB + bg) * FSTR;
        int it = 0;
        while (l2_load(fp) < GH) {
          __builtin_amdgcn_s_sleep(1);
          if (++it > 200000) break;  // bail -> wrong answer, not a hang
        }
      }
      __syncthreads();
      // drop stale L1 lines (h slot last touched at t-3); L2 is the truth
      asm volatile("buffer_inv\n\ts_waitcnt vmcnt(0)" ::: "memory");

      // GEMM2: h(t-1) @ Wh', A-frags via plain loads (L1 miss -> XCD L2 hit)
      const unsigned short* ar =
          hbuf + ((t - 1) % NSLOT) * (BATCH * KH) + (bg * BS + l15) * KH + l4 * 8;
#pragma unroll
      for (int kk = 0; kk < 10; ++kk) {
        bf16x8 a0 = *(const bf16x8*)(ar + kk * 32);
        bf16x8 a1 = *(const bf16x8*)(ar + 16 * KH + kk * 32);
#pragma unroll
        for (int g = 0; g < 4; ++g) {
          acc[g][0] = __builtin_amdgcn_mfma_f32_16x16x32_bf16(a0, bh[kk][g], acc[g][0], 0, 0, 0);
          acc[g][1] = __builtin_amdgcn_mfma_f32_16x16x32_bf16(a1, bh[kk][g], acc[g][1], 0, 0, 0);
        }
      }
    }

    // gates + state update; h(t) packed 8B, plain write-through stores -> L2
    unsigned short* hdst = hbuf + (t % NSLOT) * (BATCH * KH);
#pragma unroll
    for (int mt = 0; mt < 2; ++mt) {
#pragma unroll
      for (int r = 0; r < 4; ++r) {
        float zi = acc[0][mt][r] + bias[0];
        float zf = acc[1][mt][r] + bias[1];
        float zg = acc[2][mt][r] + bias[2];
        float zo = acc[3][mt][r] + bias[3];
        float gi = sigm(zi), gf = sigm(zf), go = sigm(zo), gg = tanhf_(zg);
        float c = gf * cst[mt][r] + gi * gg;
        cst[mt][r] = c;
        float h = go * tanhf_(c);
        unsigned v = f2b(h);
        unsigned p1 = v | ((unsigned)__shfl_xor((int)v, 1) << 16);
        unsigned long long p2 = (unsigned long long)p1 |
            ((unsigned long long)(unsigned)__shfl_xor((int)p1, 2) << 32);
        if ((l15 & 3) == 0) {
          int row = bg * BS + mt * 16 + l4 * 4 + r;
          *(unsigned long long*)(hdst + row * KH + j * SL + w * 16 + l15) = p2;
        }
      }
      acc[0][mt] = {0.f, 0.f, 0.f, 0.f};
      acc[1][mt] = {0.f, 0.f, 0.f, 0.f};
      acc[2][mt] = {0.f, 0.f, 0.f, 0.f};
      acc[3][mt] = {0.f, 0.f, 0.f, 0.f};
    }

    // release: stores ack'd in L2, then one L2-point flag add
    asm volatile("s_waitcnt vmcnt(0)" ::: "memory");
    __syncthreads();
    if (tid == 0)
      l2_atomic_add(flags + (t * GB + bg) * FSTR, 1);

    // y(t-1) duty — AFTER release (triple buffer WAR-safe); lines L1-fresh
    if (t > 0 && j == (t - 1) % GH && w < 2) {
      const unsigned short* yb =
          hbuf + ((t - 1) % NSLOT) * (BATCH * KH) + (bg * BS + w * 16 + l15) * KH + l4 * 8;
      f32x4 ay = {0.f, 0.f, 0.f, 0.f};
#pragma unroll
      for (int kk = 0; kk < 10; ++kk) {
        bf16x8 a = *(const bf16x8*)(yb + kk * 32);
        ay = __builtin_amdgcn_mfma_f32_16x16x32_bf16(a, up[kk], ay, 0, 0, 0);
      }
      if (l15 < 5) {
#pragma unroll
        for (int q = 0; q < 4; ++q) {
          int row = bg * BS + w * 16 + l4 * 4 + q;
          out[(row * TT + (t - 1)) * 5 + l15] = ay[q] + b2v;
        }
      }
    }

    // pack x(t+1)
    if (xact) {
      unsigned short* dst = &x_lds[(t + 1) & 1][xrow * XST + koff];
#pragma unroll
      for (int e = 0; e < 13; ++e)
        if (e < nf2)
          *(unsigned*)(dst + 2 * e) = (unsigned)f2b(xv[e].x) | ((unsigned)f2b(xv[e].y) << 16);
    }
    __syncthreads();

    // GEMM1(t+1)
    if (t + 1 < TT) {
      const unsigned short* xb = &x_lds[(t + 1) & 1][l15 * XST + l4 * 8];
#pragma unroll
      for (int kk = 0; kk < 5; ++kk) {
        bf16x8 a0 = *(const bf16x8*)(xb + kk * 32);
        bf16x8 a1 = *(const bf16x8*)(xb + 16 * XST + kk * 32);
#pragma unroll
        for (int g = 0; g < 4; ++g) {
          acc[g][0] = __builtin_amdgcn_mfma_f32_16x16x32_bf16(a0, bx[kk][g], acc[g][0], 0, 0, 0);
          acc[g][1] = __builtin_amdgcn_mfma_f32_16x16x32_bf16(a1, bx[kk][g], acc[g][1], 0, 0, 0);
        }
      }
    }
  }

  // epilogue: y(119)
  if (j == (TT - 1) % GH) {
    if (tid == 0) {
      int* fp = flags + ((TT - 1) * GB + bg) * FSTR;
      int it = 0;
      while (l2_load(fp) < GH) {
        __builtin_amdgcn_s_sleep(1);
        if (++it > 200000) break;
      }
    }
    __syncthreads();
    asm volatile("buffer_inv\n\ts_waitcnt vmcnt(0)" ::: "memory");
    if (w < 2) {
      const unsigned short* yb =
          hbuf + ((TT - 1) % NSLOT) * (BATCH * KH) + (bg * BS + w * 16 + l15) * KH + l4 * 8;
      f32x4 ay = {0.f, 0.f, 0.f, 0.f};
#pragma unroll
      for (int kk = 0; kk < 10; ++kk) {
        bf16x8 a = *(const bf16x8*)(yb + kk * 32);
        ay = __builtin_amdgcn_mfma_f32_16x16x32_bf16(a, up[kk], ay, 0, 0, 0);
      }
      if (l15 < 5) {
#pragma unroll
        for (int q = 0; q < 4; ++q) {
          int row = bg * BS + w * 16 + l4 * 4 + q;
          out[(row * TT + (TT - 1)) * 5 + l15] = ay[q] + b2v;
        }
      }
    }
  }
}

extern "C" void kernel_launch(void* const* d_in, const int* in_sizes, int n_in,
                              void* d_out, int out_size, void* d_ws, size_t ws_size,
                              hipStream_t stream) {
  const int*   ids   = (const int*)d_in[0];
  const float* embed = (const float*)d_in[1];
  const float* Wx    = (const float*)d_in[2];
  const float* Wh    = (const float*)d_in[3];
  const float* b     = (const float*)d_in[4];
  const float* U     = (const float*)d_in[5];
  const float* b2    = (const float*)d_in[6];
  float* out = (float*)d_out;

  char* ws = (char*)d_ws;
  size_t off = 0;
  unsigned short* Wp   = (unsigned short*)(ws + off); off += (size_t)KH * NCOL * 2;          //   819,200
  unsigned short* Wxp  = (unsigned short*)(ws + off); off += (size_t)KX * NCOL * 2;          //   409,600
  float*          bp   = (float*)(ws + off);          off += (size_t)NCOL * 4;               //     5,120
  unsigned short* Up   = (unsigned short*)(ws + off); off += (size_t)KH * 16 * 2;            //    10,240
  unsigned short* hbuf = (unsigned short*)(ws + off); off += (size_t)NSLOT * BATCH * KH * 2; // 1,966,080
  int*            flags= (int*)(ws + off);            off += (size_t)TT * GB * FSTR * 4;     //   491,520
  int*            xcd_cnt = (int*)(ws + off);         off += 8 * 4;                          //        32
  if (ws_size < off) return;  // ~3.7 MB required

  hipMemsetAsync(flags, 0, TT * GB * FSTR * 4 + 8 * 4, stream);  // flags + xcd_cnt
  k_reorder_wh<<<(KH * NCOL + 255) / 256, 256, 0, stream>>>(Wh, Wp);
  k_reorder_wx<<<(KX * NCOL + 255) / 256, 256, 0, stream>>>(Wx, Wxp);
  k_reorder_b<<<(NCOL + 255) / 256, 256, 0, stream>>>(b, bp);
  k_reorder_u<<<(KH * 16 + 255) / 256, 256, 0, stream>>>(U, Up);

  k_lstm<<<dim3(NB), dim3(256), 0, stream>>>(ids, embed, Wp, Wxp, bp, Up,
                                             hbuf, flags, xcd_cnt, b2, out);
}

// Round 7
// 905.969 us; speedup vs baseline: 20.4976x; 20.4976x over previous
//
#include <hip/hip_runtime.h>

// LSTM: VOCAB=50000, EMBED=50, NFEAT=3, T=120, HIDDEN=300, NCLASS=5, BATCH=1024
// R7: canary-validated speculative h exchange. 160 blocks = 32 bg x 5 slices,
// 1 block/CU. Producers fire relaxed-atomic 8B h-stores (no ack, no flag).
// Consumers spin { acquire-dummy (buffer_inv) -> cached int4 loads -> NaN-canary
// check } - detection fused with data transfer. Slot recycle (NSLOT=5) is
// proven safe by the data-dependency chain; block j==t%5 re-canaries (t-2)'s
// slot each step with vmcnt(0). No hand-written sc-bit asm anywhere.

#define BATCH 1024
#define TT    120
#define HID   300
#define KX    160   // padded K for x (150 -> 160)
#define KH    320   // padded K for h: 5 slices * 64
#define SL    64    // padded units per slice
#define HSL   60    // valid units per slice
#define NCOL  1280  // 5 slices * 256 packed gate columns
#define GH    5     // hidden slices
#define GB    32    // batch groups
#define BS    32    // batch rows per group
#define XST   168   // x_lds row stride in shorts (336B)
#define FSTR  32    // dummy-flag stride in ints (128B)
#define NSLOT 5
#define CAN64 0xFFFFFFFFFFFFFFFFull  // 4x bf16 -NaN: unreachable for |h|<1

typedef __attribute__((ext_vector_type(8))) short bf16x8;
typedef __attribute__((ext_vector_type(4))) float f32x4;

__device__ __forceinline__ unsigned short f2b(float f) {
  union { float f; unsigned u; } v; v.f = f;
  unsigned r = v.u + 0x7fffu + ((v.u >> 16) & 1u);
  return (unsigned short)(r >> 16);
}
__device__ __forceinline__ float sigm(float x) {
  return __builtin_amdgcn_rcpf(1.f + __expf(-x));
}
__device__ __forceinline__ float tanhf_(float x) {
  return 2.f * __builtin_amdgcn_rcpf(1.f + __expf(-2.f * x)) - 1.f;
}

// column map: c in [0,1280): j=c>>8, r=c&255, g=r>>6, u0=r&63; valid u0<60
__global__ void k_reorder_wh(const float* __restrict__ W, unsigned short* __restrict__ Wp) {
  int tid = blockIdx.x * 256 + threadIdx.x;
  if (tid >= KH * NCOL) return;
  int c = tid % NCOL, k = tid / NCOL;
  int js = k >> 6, v0 = k & 63;
  int j = c >> 8, r = c & 255, g = r >> 6, u0 = r & 63;
  float val = 0.f;
  if (v0 < HSL && u0 < HSL) val = W[(js * HSL + v0) * 1200 + g * 300 + j * HSL + u0];
  Wp[((k >> 3) * NCOL + c) * 8 + (k & 7)] = f2b(val);
}

__global__ void k_reorder_wx(const float* __restrict__ W, unsigned short* __restrict__ Wp) {
  int tid = blockIdx.x * 256 + threadIdx.x;
  if (tid >= KX * NCOL) return;
  int c = tid % NCOL, k = tid / NCOL;
  int j = c >> 8, r = c & 255, g = r >> 6, u0 = r & 63;
  float val = 0.f;
  if (k < 150 && u0 < HSL) val = W[k * 1200 + g * 300 + j * HSL + u0];
  Wp[((k >> 3) * NCOL + c) * 8 + (k & 7)] = f2b(val);
}

__global__ void k_reorder_b(const float* __restrict__ b, float* __restrict__ bp) {
  int c = blockIdx.x * 256 + threadIdx.x;
  if (c >= NCOL) return;
  int j = c >> 8, r = c & 255, g = r >> 6, u0 = r & 63;
  bp[c] = (u0 < HSL) ? b[g * 300 + j * HSL + u0] : 0.f;
}

__global__ void k_reorder_u(const float* __restrict__ U, unsigned short* __restrict__ Up) {
  int tid = blockIdx.x * 256 + threadIdx.x;
  if (tid >= KH * 16) return;
  int n = tid % 16, k = tid / 16;
  int js = k >> 6, v0 = k & 63;
  float v = (v0 < HSL && n < 5) ? U[(js * HSL + v0) * 5 + n] : 0.f;
  Up[((k >> 3) * 16 + n) * 8 + (k & 7)] = f2b(v);
}

__device__ __forceinline__ unsigned is_canary(bf16x8 v) {
  int4 q = __builtin_bit_cast(int4, v);
  return (unsigned)(((q.x & q.y) == -1) | ((q.z & q.w) == -1));
}

__launch_bounds__(256, 1)
__global__ void k_lstm(const int* __restrict__ ids, const float* __restrict__ embed,
                       const unsigned short* __restrict__ Wp,
                       const unsigned short* __restrict__ Wxp,
                       const float* __restrict__ bp,
                       const unsigned short* __restrict__ Up,
                       unsigned short* __restrict__ hbuf,   // [5][1024][320] bf16
                       int* __restrict__ flags,             // dummy acquire targets
                       const float* __restrict__ b2,
                       float* __restrict__ out) {
  __shared__ __align__(16) unsigned short x_lds[2][BS * XST];

  const int tid = threadIdx.x;
  const int bid = blockIdx.x;
  const int bg = bid / GH, j = bid % GH;
  const int lane = tid & 63, w = tid >> 6;  // 4 waves; wave w owns units w*16..+15
  const int l15 = lane & 15, l4 = lane >> 4;

  if (tid < BS) {
#pragma unroll
    for (int bq = 0; bq < 2; ++bq)
      for (int e = 150; e < XST; ++e) x_lds[bq][tid * XST + e] = 0;
  }

  const int colb = j * 256 + w * 16 + l15;

  // persistent B fragments (linear k-pack: elem e of k-row (kk*4+l4) is k=kk*32+l4*8+e)
  bf16x8 bh[10][4], bx[5][4];
#pragma unroll
  for (int kk = 0; kk < 10; ++kk)
#pragma unroll
    for (int g = 0; g < 4; ++g)
      bh[kk][g] = *(const bf16x8*)(Wp + ((kk * 4 + l4) * NCOL + colb + g * 64) * 8);
#pragma unroll
  for (int kk = 0; kk < 5; ++kk)
#pragma unroll
    for (int g = 0; g < 4; ++g)
      bx[kk][g] = *(const bf16x8*)(Wxp + ((kk * 4 + l4) * NCOL + colb + g * 64) * 8);

  float bias[4];
#pragma unroll
  for (int g = 0; g < 4; ++g) bias[g] = bp[colb + g * 64];
  const float b2v = (l15 < 5) ? b2[l15] : 0.f;

  // ---- x(0) gather: 192 threads = 32 rows x 3 feats x 2 halves (26/24 split)
  if (tid < 192) {
    int xrow = tid / 6, half = tid % 6, f = half >> 1, hh = half & 1;
    int nf2 = hh ? 12 : 13;
    int koff = f * 50 + (hh ? 26 : 0);
    int id = ids[((bg * BS + xrow) * TT + 0) * 3 + f];
    const float* src = embed + (long)id * 50 + (hh ? 26 : 0);
    unsigned short* dst = &x_lds[0][xrow * XST + koff];
#pragma unroll
    for (int e = 0; e < 13; ++e)
      if (e < nf2) {
        float2 v = *(const float2*)(src + 2 * e);
        *(unsigned*)(dst + 2 * e) = (unsigned)f2b(v.x) | ((unsigned)f2b(v.y) << 16);
      }
  }
  __syncthreads();

  f32x4 acc[4][2];
  float cst[2][4];
#pragma unroll
  for (int g = 0; g < 4; ++g)
#pragma unroll
    for (int mt = 0; mt < 2; ++mt) acc[g][mt] = {0.f, 0.f, 0.f, 0.f};
#pragma unroll
  for (int mt = 0; mt < 2; ++mt)
#pragma unroll
    for (int r = 0; r < 4; ++r) cst[mt][r] = 0.f;

  // GEMM1(0)
  {
    const unsigned short* xb = &x_lds[0][l15 * XST + l4 * 8];
#pragma unroll
    for (int kk = 0; kk < 5; ++kk) {
      bf16x8 a0 = *(const bf16x8*)(xb + kk * 32);
      bf16x8 a1 = *(const bf16x8*)(xb + 16 * XST + kk * 32);
#pragma unroll
      for (int g = 0; g < 4; ++g) {
        acc[g][0] = __builtin_amdgcn_mfma_f32_16x16x32_bf16(a0, bx[kk][g], acc[g][0], 0, 0, 0);
        acc[g][1] = __builtin_amdgcn_mfma_f32_16x16x32_bf16(a1, bx[kk][g], acc[g][1], 0, 0, 0);
      }
    }
  }

  bf16x8 va0[10], va1[10];

  for (int t = 0; t < TT; ++t) {
    // issue x(t+1) loads first (read-only; stale-cache-safe)
    float2 xv[13];
    int xrow = 0, koff = 0, nf2 = 0;
    const bool xact = (t + 1 < TT) && (tid < 192);
    if (xact) {
      xrow = tid / 6; int half = tid % 6, f = half >> 1, hh = half & 1;
      nf2 = hh ? 12 : 13;
      koff = f * 50 + (hh ? 26 : 0);
      int id = ids[((bg * BS + xrow) * TT + (t + 1)) * 3 + f];
      const float* src = embed + (long)id * 50 + (hh ? 26 : 0);
#pragma unroll
      for (int e = 0; e < 13; ++e)
        if (e < nf2) xv[e] = *(const float2*)(src + 2 * e);
    }

    if (t > 0) {
      // validate-load h(t-1): acquire-inv fused with cached refill + canary check
      const unsigned short* ar =
          hbuf + ((t - 1) % NSLOT) * (BATCH * KH) + (bg * BS + l15) * KH + l4 * 8;
      int it = 0;
      while (true) {
        (void)__hip_atomic_load(&flags[bg * FSTR], __ATOMIC_ACQUIRE,
                                __HIP_MEMORY_SCOPE_AGENT);  // emits buffer_inv
        unsigned bad = 0;
#pragma unroll
        for (int kk = 0; kk < 10; ++kk) {
          va0[kk] = *(const bf16x8*)(ar + kk * 32);
          va1[kk] = *(const bf16x8*)(ar + 16 * KH + kk * 32);
        }
#pragma unroll
        for (int kk = 0; kk < 10; ++kk) {
          bad |= is_canary(va0[kk]);
          bad |= is_canary(va1[kk]);
        }
        if (!__any((int)bad)) break;
        if (++it > 20000) break;  // bail -> NaN output (loud), not a hang
      }
      asm volatile("" ::: "memory");  // keep atomic ops below after the loads

      // GEMM2: h(t-1) @ Wh'
#pragma unroll
      for (int kk = 0; kk < 10; ++kk) {
#pragma unroll
        for (int g = 0; g < 4; ++g) {
          acc[g][0] = __builtin_amdgcn_mfma_f32_16x16x32_bf16(va0[kk], bh[kk][g], acc[g][0], 0, 0, 0);
          acc[g][1] = __builtin_amdgcn_mfma_f32_16x16x32_bf16(va1[kk], bh[kk][g], acc[g][1], 0, 0, 0);
        }
      }
    }

    // gates + state update; h(t) packed 8B relaxed-atomic stores (fire-and-forget)
    unsigned short* hdst = hbuf + (t % NSLOT) * (BATCH * KH);
#pragma unroll
    for (int mt = 0; mt < 2; ++mt) {
#pragma unroll
      for (int r = 0; r < 4; ++r) {
        float zi = acc[0][mt][r] + bias[0];
        float zf = acc[1][mt][r] + bias[1];
        float zg = acc[2][mt][r] + bias[2];
        float zo = acc[3][mt][r] + bias[3];
        float gi = sigm(zi), gf = sigm(zf), go = sigm(zo), gg = tanhf_(zg);
        float c = gf * cst[mt][r] + gi * gg;
        cst[mt][r] = c;
        float h = go * tanhf_(c);
        unsigned v = f2b(h);
        unsigned p1 = v | ((unsigned)__shfl_xor((int)v, 1) << 16);
        unsigned long long p2 = (unsigned long long)p1 |
            ((unsigned long long)(unsigned)__shfl_xor((int)p1, 2) << 32);
        if ((l15 & 3) == 0) {
          int row = bg * BS + mt * 16 + l4 * 4 + r;
          __hip_atomic_store((unsigned long long*)(hdst + row * KH + j * SL + w * 16 + l15),
                             p2, __ATOMIC_RELAXED, __HIP_MEMORY_SCOPE_AGENT);
        }
      }
      acc[0][mt] = {0.f, 0.f, 0.f, 0.f};
      acc[1][mt] = {0.f, 0.f, 0.f, 0.f};
      acc[2][mt] = {0.f, 0.f, 0.f, 0.f};
      acc[3][mt] = {0.f, 0.f, 0.f, 0.f};
    }

    // re-canary slot (t-2)%5 (all reads provably done); ack before moving on
    if (t >= 2 && j == t % GH) {
      unsigned long long* cb =
          (unsigned long long*)(hbuf + ((t - 2) % NSLOT) * (BATCH * KH) + bg * BS * KH);
#pragma unroll
      for (int p = 0; p < 10; ++p)
        __hip_atomic_store(cb + tid + 256 * p, CAN64, __ATOMIC_RELAXED,
                           __HIP_MEMORY_SCOPE_AGENT);
      asm volatile("s_waitcnt vmcnt(0)" ::: "memory");
    }

    // y(t-1) duty straight from the A-frags already in registers (no re-read)
    if (t > 0 && j == (t - 1) % GH && w == 0) {
      f32x4 ay0 = {0.f, 0.f, 0.f, 0.f}, ay1 = {0.f, 0.f, 0.f, 0.f};
#pragma unroll
      for (int kk = 0; kk < 10; ++kk) {
        bf16x8 u = *(const bf16x8*)(Up + ((kk * 4 + l4) * 16 + l15) * 8);
        ay0 = __builtin_amdgcn_mfma_f32_16x16x32_bf16(va0[kk], u, ay0, 0, 0, 0);
        ay1 = __builtin_amdgcn_mfma_f32_16x16x32_bf16(va1[kk], u, ay1, 0, 0, 0);
      }
      if (l15 < 5) {
#pragma unroll
        for (int q = 0; q < 4; ++q) {
          out[((bg * BS + l4 * 4 + q) * TT + (t - 1)) * 5 + l15] = ay0[q] + b2v;
          out[((bg * BS + 16 + l4 * 4 + q) * TT + (t - 1)) * 5 + l15] = ay1[q] + b2v;
        }
      }
    }

    // pack x(t+1)
    if (xact) {
      unsigned short* dst = &x_lds[(t + 1) & 1][xrow * XST + koff];
#pragma unroll
      for (int e = 0; e < 13; ++e)
        if (e < nf2)
          *(unsigned*)(dst + 2 * e) = (unsigned)f2b(xv[e].x) | ((unsigned)f2b(xv[e].y) << 16);
    }
    __syncthreads();

    // GEMM1(t+1)
    if (t + 1 < TT) {
      const unsigned short* xb = &x_lds[(t + 1) & 1][l15 * XST + l4 * 8];
#pragma unroll
      for (int kk = 0; kk < 5; ++kk) {
        bf16x8 a0 = *(const bf16x8*)(xb + kk * 32);
        bf16x8 a1 = *(const bf16x8*)(xb + 16 * XST + kk * 32);
#pragma unroll
        for (int g = 0; g < 4; ++g) {
          acc[g][0] = __builtin_amdgcn_mfma_f32_16x16x32_bf16(a0, bx[kk][g], acc[g][0], 0, 0, 0);
          acc[g][1] = __builtin_amdgcn_mfma_f32_16x16x32_bf16(a1, bx[kk][g], acc[g][1], 0, 0, 0);
        }
      }
    }
  }

  // epilogue: y(119) by slice (TT-1)%5, validating slot (TT-1)%5
  if (j == (TT - 1) % GH) {
    const unsigned short* ar =
        hbuf + ((TT - 1) % NSLOT) * (BATCH * KH) + (bg * BS + l15) * KH + l4 * 8;
    int it = 0;
    while (true) {
      (void)__hip_atomic_load(&flags[bg * FSTR], __ATOMIC_ACQUIRE,
                              __HIP_MEMORY_SCOPE_AGENT);
      unsigned bad = 0;
#pragma unroll
      for (int kk = 0; kk < 10; ++kk) {
        va0[kk] = *(const bf16x8*)(ar + kk * 32);
        va1[kk] = *(const bf16x8*)(ar + 16 * KH + kk * 32);
      }
#pragma unroll
      for (int kk = 0; kk < 10; ++kk) {
        bad |= is_canary(va0[kk]);
        bad |= is_canary(va1[kk]);
      }
      if (!__any((int)bad)) break;
      if (++it > 20000) break;
    }
    asm volatile("" ::: "memory");
    if (w == 0) {
      f32x4 ay0 = {0.f, 0.f, 0.f, 0.f}, ay1 = {0.f, 0.f, 0.f, 0.f};
#pragma unroll
      for (int kk = 0; kk < 10; ++kk) {
        bf16x8 u = *(const bf16x8*)(Up + ((kk * 4 + l4) * 16 + l15) * 8);
        ay0 = __builtin_amdgcn_mfma_f32_16x16x32_bf16(va0[kk], u, ay0, 0, 0, 0);
        ay1 = __builtin_amdgcn_mfma_f32_16x16x32_bf16(va1[kk], u, ay1, 0, 0, 0);
      }
      if (l15 < 5) {
#pragma unroll
        for (int q = 0; q < 4; ++q) {
          out[((bg * BS + l4 * 4 + q) * TT + (TT - 1)) * 5 + l15] = ay0[q] + b2v;
          out[((bg * BS + 16 + l4 * 4 + q) * TT + (TT - 1)) * 5 + l15] = ay1[q] + b2v;
        }
      }
    }
  }
}

extern "C" void kernel_launch(void* const* d_in, const int* in_sizes, int n_in,
                              void* d_out, int out_size, void* d_ws, size_t ws_size,
                              hipStream_t stream) {
  const int*   ids   = (const int*)d_in[0];
  const float* embed = (const float*)d_in[1];
  const float* Wx    = (const float*)d_in[2];
  const float* Wh    = (const float*)d_in[3];
  const float* b     = (const float*)d_in[4];
  const float* U     = (const float*)d_in[5];
  const float* b2    = (const float*)d_in[6];
  float* out = (float*)d_out;

  char* ws = (char*)d_ws;
  size_t off = 0;
  unsigned short* Wp   = (unsigned short*)(ws + off); off += (size_t)KH * NCOL * 2;          //   819,200
  unsigned short* Wxp  = (unsigned short*)(ws + off); off += (size_t)KX * NCOL * 2;          //   409,600
  float*          bp   = (float*)(ws + off);          off += (size_t)NCOL * 4;               //     5,120
  unsigned short* Up   = (unsigned short*)(ws + off); off += (size_t)KH * 16 * 2;            //    10,240
  unsigned short* hbuf = (unsigned short*)(ws + off); off += (size_t)NSLOT * BATCH * KH * 2; // 3,276,800
  int*            flags= (int*)(ws + off);            off += (size_t)GB * FSTR * 4;          //     4,096
  if (ws_size < off) return;  // ~4.5 MB required

  hipMemsetAsync(hbuf, 0xFF, (size_t)NSLOT * BATCH * KH * 2, stream);  // canaries
  hipMemsetAsync(flags, 0, GB * FSTR * 4, stream);
  k_reorder_wh<<<(KH * NCOL + 255) / 256, 256, 0, stream>>>(Wh, Wp);
  k_reorder_wx<<<(KX * NCOL + 255) / 256, 256, 0, stream>>>(Wx, Wxp);
  k_reorder_b<<<(NCOL + 255) / 256, 256, 0, stream>>>(b, bp);
  k_reorder_u<<<(KH * 16 + 255) / 256, 256, 0, stream>>>(U, Up);

  k_lstm<<<dim3(GB * GH), dim3(256), 0, stream>>>(ids, embed, Wp, Wxp, bp, Up,
                                                  hbuf, flags, b2, out);
}

// Round 8
// 717.528 us; speedup vs baseline: 25.8808x; 1.2626x over previous
//
#include <hip/hip_runtime.h>

// LSTM: VOCAB=50000, EMBED=50, NFEAT=3, T=120, HIDDEN=300, NCLASS=5, BATCH=1024
// R8: XCD-local h exchange with ZERO L2 invalidation.
//  - 256 blocks, 83KB LDS -> 1 block/CU -> exactly 32 blocks/XCD; XCC_ID
//    ranking maps bgs 4x..4x+3 (5 slices each) onto XCD x. (proven R6)
//  - h: plain write-through stores -> local L2; consumers: buffer_inv (L1
//    only) + plain cached loads -> L2 hits. (visibility proven R6)
//  - flags: compiler __hip_atomic add/load RELAXED+AGENT (fast pair proven
//    R5). NO acquire anywhere -> embed/ids stay L2-cached.

#define BATCH 1024
#define TT    120
#define HID   300
#define KX    160   // padded K for x (150 -> 160)
#define KH    320   // padded K for h: 5 slices * 64
#define SL    64    // padded units per slice
#define HSL   60    // valid units per slice
#define NCOL  1280  // 5 slices * 256 packed gate columns
#define GH    5     // hidden slices
#define GB    32    // batch groups
#define BS    32    // batch rows per group
#define XST   168   // x_lds row stride in shorts (336B)
#define FSTR  32    // flag stride in ints (128B)
#define NSLOT 3
#define NB    256   // blocks launched (1 per CU)

typedef __attribute__((ext_vector_type(8))) short bf16x8;
typedef __attribute__((ext_vector_type(4))) float f32x4;

__device__ __forceinline__ unsigned short f2b(float f) {
  union { float f; unsigned u; } v; v.f = f;
  unsigned r = v.u + 0x7fffu + ((v.u >> 16) & 1u);
  return (unsigned short)(r >> 16);
}
__device__ __forceinline__ float sigm(float x) {
  return __builtin_amdgcn_rcpf(1.f + __expf(-x));
}
__device__ __forceinline__ float tanhf_(float x) {
  return 2.f * __builtin_amdgcn_rcpf(1.f + __expf(-2.f * x)) - 1.f;
}

// column map: c in [0,1280): j=c>>8, r=c&255, g=r>>6, u0=r&63; valid u0<60
__global__ void k_reorder_wh(const float* __restrict__ W, unsigned short* __restrict__ Wp) {
  int tid = blockIdx.x * 256 + threadIdx.x;
  if (tid >= KH * NCOL) return;
  int c = tid % NCOL, k = tid / NCOL;
  int js = k >> 6, v0 = k & 63;
  int j = c >> 8, r = c & 255, g = r >> 6, u0 = r & 63;
  float val = 0.f;
  if (v0 < HSL && u0 < HSL) val = W[(js * HSL + v0) * 1200 + g * 300 + j * HSL + u0];
  Wp[((k >> 3) * NCOL + c) * 8 + (k & 7)] = f2b(val);
}

__global__ void k_reorder_wx(const float* __restrict__ W, unsigned short* __restrict__ Wp) {
  int tid = blockIdx.x * 256 + threadIdx.x;
  if (tid >= KX * NCOL) return;
  int c = tid % NCOL, k = tid / NCOL;
  int j = c >> 8, r = c & 255, g = r >> 6, u0 = r & 63;
  float val = 0.f;
  if (k < 150 && u0 < HSL) val = W[k * 1200 + g * 300 + j * HSL + u0];
  Wp[((k >> 3) * NCOL + c) * 8 + (k & 7)] = f2b(val);
}

__global__ void k_reorder_b(const float* __restrict__ b, float* __restrict__ bp) {
  int c = blockIdx.x * 256 + threadIdx.x;
  if (c >= NCOL) return;
  int j = c >> 8, r = c & 255, g = r >> 6, u0 = r & 63;
  bp[c] = (u0 < HSL) ? b[g * 300 + j * HSL + u0] : 0.f;
}

__global__ void k_reorder_u(const float* __restrict__ U, unsigned short* __restrict__ Up) {
  int tid = blockIdx.x * 256 + threadIdx.x;
  if (tid >= KH * 16) return;
  int n = tid % 16, k = tid / 16;
  int js = k >> 6, v0 = k & 63;
  float v = (v0 < HSL && n < 5) ? U[(js * HSL + v0) * 5 + n] : 0.f;
  Up[((k >> 3) * 16 + n) * 8 + (k & 7)] = f2b(v);
}

__launch_bounds__(256, 1)
__global__ void k_lstm(const int* __restrict__ ids, const float* __restrict__ embed,
                       const unsigned short* __restrict__ Wp,
                       const unsigned short* __restrict__ Wxp,
                       const float* __restrict__ bp,
                       const unsigned short* __restrict__ Up,
                       unsigned short* __restrict__ hbuf,   // [3][1024][320] bf16
                       int* __restrict__ flags,             // [120][32] @128B
                       int* __restrict__ xcd_cnt,           // [8]
                       const float* __restrict__ b2,
                       float* __restrict__ out) {
  __shared__ __align__(16) unsigned short x_lds[2][BS * XST];
  __shared__ char lds_pad[61440];   // force 1 block/CU (total LDS > 80KB)
  __shared__ int role[2];

  const int tid = threadIdx.x;
  if (tid == 0) {
    ((volatile char*)lds_pad)[0] = 0;  // keep pad allocated
    int xcd = __builtin_amdgcn_s_getreg(63508) & 7;  // HW_REG_XCC_ID (id20,sz32)
    int rank = atomicAdd(&xcd_cnt[xcd], 1);
    role[0] = xcd; role[1] = rank;
  }
  __syncthreads();
  const int xcd = role[0], rank = role[1];
  if (rank >= GH * 4) return;               // spare block
  const int bg = xcd * 4 + rank / GH;       // 8 XCDs x 4 bgs = 32
  const int j  = rank % GH;

  const int lane = tid & 63, w = tid >> 6;  // 4 waves; wave w owns units w*16..+15
  const int l15 = lane & 15, l4 = lane >> 4;

  if (tid < BS) {
#pragma unroll
    for (int bq = 0; bq < 2; ++bq)
      for (int e = 150; e < XST; ++e) x_lds[bq][tid * XST + e] = 0;
  }

  const int colb = j * 256 + w * 16 + l15;

  // persistent B fragments (linear k-pack: elem e of k-row (kk*4+l4) is k=kk*32+l4*8+e)
  bf16x8 bh[10][4], bx[5][4];
#pragma unroll
  for (int kk = 0; kk < 10; ++kk)
#pragma unroll
    for (int g = 0; g < 4; ++g)
      bh[kk][g] = *(const bf16x8*)(Wp + ((kk * 4 + l4) * NCOL + colb + g * 64) * 8);
#pragma unroll
  for (int kk = 0; kk < 5; ++kk)
#pragma unroll
    for (int g = 0; g < 4; ++g)
      bx[kk][g] = *(const bf16x8*)(Wxp + ((kk * 4 + l4) * NCOL + colb + g * 64) * 8);

  float bias[4];
#pragma unroll
  for (int g = 0; g < 4; ++g) bias[g] = bp[colb + g * 64];
  const float b2v = (l15 < 5) ? b2[l15] : 0.f;

  // ---- x(0) gather: 192 threads = 32 rows x 3 feats x 2 halves (26/24 split)
  if (tid < 192) {
    int xrow = tid / 6, half = tid % 6, f = half >> 1, hh = half & 1;
    int nf2 = hh ? 12 : 13;
    int koff = f * 50 + (hh ? 26 : 0);
    int id = ids[((bg * BS + xrow) * TT + 0) * 3 + f];
    const float* src = embed + (long)id * 50 + (hh ? 26 : 0);
    unsigned short* dst = &x_lds[0][xrow * XST + koff];
#pragma unroll
    for (int e = 0; e < 13; ++e)
      if (e < nf2) {
        float2 v = *(const float2*)(src + 2 * e);
        *(unsigned*)(dst + 2 * e) = (unsigned)f2b(v.x) | ((unsigned)f2b(v.y) << 16);
      }
  }
  __syncthreads();

  f32x4 acc[4][2];
  float cst[2][4];
#pragma unroll
  for (int g = 0; g < 4; ++g)
#pragma unroll
    for (int mt = 0; mt < 2; ++mt) acc[g][mt] = {0.f, 0.f, 0.f, 0.f};
#pragma unroll
  for (int mt = 0; mt < 2; ++mt)
#pragma unroll
    for (int r = 0; r < 4; ++r) cst[mt][r] = 0.f;

  // GEMM1(0)
  {
    const unsigned short* xb = &x_lds[0][l15 * XST + l4 * 8];
#pragma unroll
    for (int kk = 0; kk < 5; ++kk) {
      bf16x8 a0 = *(const bf16x8*)(xb + kk * 32);
      bf16x8 a1 = *(const bf16x8*)(xb + 16 * XST + kk * 32);
#pragma unroll
      for (int g = 0; g < 4; ++g) {
        acc[g][0] = __builtin_amdgcn_mfma_f32_16x16x32_bf16(a0, bx[kk][g], acc[g][0], 0, 0, 0);
        acc[g][1] = __builtin_amdgcn_mfma_f32_16x16x32_bf16(a1, bx[kk][g], acc[g][1], 0, 0, 0);
      }
    }
  }

  bf16x8 va0[10], va1[10];

  for (int t = 0; t < TT; ++t) {
    // issue x(t+1) loads first (read-only; caches stay valid all kernel)
    float2 xv[13];
    int xrow = 0, koff = 0, nf2 = 0;
    const bool xact = (t + 1 < TT) && (tid < 192);
    if (xact) {
      xrow = tid / 6; int half = tid % 6, f = half >> 1, hh = half & 1;
      nf2 = hh ? 12 : 13;
      koff = f * 50 + (hh ? 26 : 0);
      int id = ids[((bg * BS + xrow) * TT + (t + 1)) * 3 + f];
      const float* src = embed + (long)id * 50 + (hh ? 26 : 0);
#pragma unroll
      for (int e = 0; e < 13; ++e)
        if (e < nf2) xv[e] = *(const float2*)(src + 2 * e);
    }

    if (t > 0) {
      if (tid == 0) {  // relaxed poll (R5-proven atomic pair; no cache ops)
        int* fp = flags + ((t - 1) * GB + bg) * FSTR;
        int it = 0;
        while (__hip_atomic_load(fp, __ATOMIC_RELAXED, __HIP_MEMORY_SCOPE_AGENT) < GH) {
          __builtin_amdgcn_s_sleep(1);
          if (++it > 200000) break;  // bail -> wrong answer, not a hang
        }
      }
      __syncthreads();
      // drop stale L1 lines only; XCD L2 holds partners' fresh h (R6-proven)
      asm volatile("buffer_inv\n\ts_waitcnt vmcnt(0)" ::: "memory");

      // load h(t-1) A-frags via plain cached loads (L1 miss -> local L2 hit)
      const unsigned short* ar =
          hbuf + ((t - 1) % NSLOT) * (BATCH * KH) + (bg * BS + l15) * KH + l4 * 8;
#pragma unroll
      for (int kk = 0; kk < 10; ++kk) {
        va0[kk] = *(const bf16x8*)(ar + kk * 32);
        va1[kk] = *(const bf16x8*)(ar + 16 * KH + kk * 32);
      }

      // GEMM2: h(t-1) @ Wh'
#pragma unroll
      for (int kk = 0; kk < 10; ++kk) {
#pragma unroll
        for (int g = 0; g < 4; ++g) {
          acc[g][0] = __builtin_amdgcn_mfma_f32_16x16x32_bf16(va0[kk], bh[kk][g], acc[g][0], 0, 0, 0);
          acc[g][1] = __builtin_amdgcn_mfma_f32_16x16x32_bf16(va1[kk], bh[kk][g], acc[g][1], 0, 0, 0);
        }
      }
    }

    // gates + state update; h(t) packed 8B plain write-through stores -> local L2
    unsigned short* hdst = hbuf + (t % NSLOT) * (BATCH * KH);
#pragma unroll
    for (int mt = 0; mt < 2; ++mt) {
#pragma unroll
      for (int r = 0; r < 4; ++r) {
        float zi = acc[0][mt][r] + bias[0];
        float zf = acc[1][mt][r] + bias[1];
        float zg = acc[2][mt][r] + bias[2];
        float zo = acc[3][mt][r] + bias[3];
        float gi = sigm(zi), gf = sigm(zf), go = sigm(zo), gg = tanhf_(zg);
        float c = gf * cst[mt][r] + gi * gg;
        cst[mt][r] = c;
        float h = go * tanhf_(c);
        unsigned v = f2b(h);
        unsigned p1 = v | ((unsigned)__shfl_xor((int)v, 1) << 16);
        unsigned long long p2 = (unsigned long long)p1 |
            ((unsigned long long)(unsigned)__shfl_xor((int)p1, 2) << 32);
        if ((l15 & 3) == 0) {
          int row = bg * BS + mt * 16 + l4 * 4 + r;
          *(unsigned long long*)(hdst + row * KH + j * SL + w * 16 + l15) = p2;
        }
      }
      acc[0][mt] = {0.f, 0.f, 0.f, 0.f};
      acc[1][mt] = {0.f, 0.f, 0.f, 0.f};
      acc[2][mt] = {0.f, 0.f, 0.f, 0.f};
      acc[3][mt] = {0.f, 0.f, 0.f, 0.f};
    }

    // release: h stores L2-acked, then one relaxed flag add (R5-proven pair)
    asm volatile("s_waitcnt vmcnt(0)" ::: "memory");
    __syncthreads();
    if (tid == 0)
      __hip_atomic_fetch_add(flags + (t * GB + bg) * FSTR, 1, __ATOMIC_RELAXED,
                             __HIP_MEMORY_SCOPE_AGENT);

    // y(t-1) duty straight from A-frags already in registers (no re-read)
    if (t > 0 && j == (t - 1) % GH && w == 0) {
      f32x4 ay0 = {0.f, 0.f, 0.f, 0.f}, ay1 = {0.f, 0.f, 0.f, 0.f};
#pragma unroll
      for (int kk = 0; kk < 10; ++kk) {
        bf16x8 u = *(const bf16x8*)(Up + ((kk * 4 + l4) * 16 + l15) * 8);
        ay0 = __builtin_amdgcn_mfma_f32_16x16x32_bf16(va0[kk], u, ay0, 0, 0, 0);
        ay1 = __builtin_amdgcn_mfma_f32_16x16x32_bf16(va1[kk], u, ay1, 0, 0, 0);
      }
      if (l15 < 5) {
#pragma unroll
        for (int q = 0; q < 4; ++q) {
          out[((bg * BS + l4 * 4 + q) * TT + (t - 1)) * 5 + l15] = ay0[q] + b2v;
          out[((bg * BS + 16 + l4 * 4 + q) * TT + (t - 1)) * 5 + l15] = ay1[q] + b2v;
        }
      }
    }

    // pack x(t+1)
    if (xact) {
      unsigned short* dst = &x_lds[(t + 1) & 1][xrow * XST + koff];
#pragma unroll
      for (int e = 0; e < 13; ++e)
        if (e < nf2)
          *(unsigned*)(dst + 2 * e) = (unsigned)f2b(xv[e].x) | ((unsigned)f2b(xv[e].y) << 16);
    }
    __syncthreads();

    // GEMM1(t+1)
    if (t + 1 < TT) {
      const unsigned short* xb = &x_lds[(t + 1) & 1][l15 * XST + l4 * 8];
#pragma unroll
      for (int kk = 0; kk < 5; ++kk) {
        bf16x8 a0 = *(const bf16x8*)(xb + kk * 32);
        bf16x8 a1 = *(const bf16x8*)(xb + 16 * XST + kk * 32);
#pragma unroll
        for (int g = 0; g < 4; ++g) {
          acc[g][0] = __builtin_amdgcn_mfma_f32_16x16x32_bf16(a0, bx[kk][g], acc[g][0], 0, 0, 0);
          acc[g][1] = __builtin_amdgcn_mfma_f32_16x16x32_bf16(a1, bx[kk][g], acc[g][1], 0, 0, 0);
        }
      }
    }
  }

  // epilogue: y(119) by slice (TT-1)%5
  if (j == (TT - 1) % GH) {
    if (tid == 0) {
      int* fp = flags + ((TT - 1) * GB + bg) * FSTR;
      int it = 0;
      while (__hip_atomic_load(fp, __ATOMIC_RELAXED, __HIP_MEMORY_SCOPE_AGENT) < GH) {
        __builtin_amdgcn_s_sleep(1);
        if (++it > 200000) break;
      }
    }
    __syncthreads();
    asm volatile("buffer_inv\n\ts_waitcnt vmcnt(0)" ::: "memory");
    const unsigned short* ar =
        hbuf + ((TT - 1) % NSLOT) * (BATCH * KH) + (bg * BS + l15) * KH + l4 * 8;
#pragma unroll
    for (int kk = 0; kk < 10; ++kk) {
      va0[kk] = *(const bf16x8*)(ar + kk * 32);
      va1[kk] = *(const bf16x8*)(ar + 16 * KH + kk * 32);
    }
    if (w == 0) {
      f32x4 ay0 = {0.f, 0.f, 0.f, 0.f}, ay1 = {0.f, 0.f, 0.f, 0.f};
#pragma unroll
      for (int kk = 0; kk < 10; ++kk) {
        bf16x8 u = *(const bf16x8*)(Up + ((kk * 4 + l4) * 16 + l15) * 8);
        ay0 = __builtin_amdgcn_mfma_f32_16x16x32_bf16(va0[kk], u, ay0, 0, 0, 0);
        ay1 = __builtin_amdgcn_mfma_f32_16x16x32_bf16(va1[kk], u, ay1, 0, 0, 0);
      }
      if (l15 < 5) {
#pragma unroll
        for (int q = 0; q < 4; ++q) {
          out[((bg * BS + l4 * 4 + q) * TT + (TT - 1)) * 5 + l15] = ay0[q] + b2v;
          out[((bg * BS + 16 + l4 * 4 + q) * TT + (TT - 1)) * 5 + l15] = ay1[q] + b2v;
        }
      }
    }
  }
}

extern "C" void kernel_launch(void* const* d_in, const int* in_sizes, int n_in,
                              void* d_out, int out_size, void* d_ws, size_t ws_size,
                              hipStream_t stream) {
  const int*   ids   = (const int*)d_in[0];
  const float* embed = (const float*)d_in[1];
  const float* Wx    = (const float*)d_in[2];
  const float* Wh    = (const float*)d_in[3];
  const float* b     = (const float*)d_in[4];
  const float* U     = (const float*)d_in[5];
  const float* b2    = (const float*)d_in[6];
  float* out = (float*)d_out;

  char* ws = (char*)d_ws;
  size_t off = 0;
  unsigned short* Wp   = (unsigned short*)(ws + off); off += (size_t)KH * NCOL * 2;          //   819,200
  unsigned short* Wxp  = (unsigned short*)(ws + off); off += (size_t)KX * NCOL * 2;          //   409,600
  float*          bp   = (float*)(ws + off);          off += (size_t)NCOL * 4;               //     5,120
  unsigned short* Up   = (unsigned short*)(ws + off); off += (size_t)KH * 16 * 2;            //    10,240
  unsigned short* hbuf = (unsigned short*)(ws + off); off += (size_t)NSLOT * BATCH * KH * 2; // 1,966,080
  int*            flags= (int*)(ws + off);            off += (size_t)TT * GB * FSTR * 4;     //   491,520
  int*            xcd_cnt = (int*)(ws + off);         off += 8 * 4;                          //        32
  if (ws_size < off) return;  // ~3.7 MB required

  hipMemsetAsync(flags, 0, TT * GB * FSTR * 4 + 8 * 4, stream);  // flags + xcd_cnt
  k_reorder_wh<<<(KH * NCOL + 255) / 256, 256, 0, stream>>>(Wh, Wp);
  k_reorder_wx<<<(KX * NCOL + 255) / 256, 256, 0, stream>>>(Wx, Wxp);
  k_reorder_b<<<(NCOL + 255) / 256, 256, 0, stream>>>(b, bp);
  k_reorder_u<<<(KH * 16 + 255) / 256, 256, 0, stream>>>(U, Up);

  k_lstm<<<dim3(NB), dim3(256), 0, stream>>>(ids, embed, Wp, Wxp, bp, Up,
                                             hbuf, flags, xcd_cnt, b2, out);
}

// Round 10
// 711.770 us; speedup vs baseline: 26.0902x; 1.0081x over previous
//
#include <hip/hip_runtime.h>

// LSTM: VOCAB=50000, EMBED=50, NFEAT=3, T=120, HIDDEN=300, NCLASS=5, BATCH=1024
// R10 = R8's PROVEN sync protocol (compiler atomics only: relaxed-AGENT
// fetch_add release / relaxed-AGENT load poll; buffer_inv+vmcnt before h reads)
// with the barriers trimmed:
//  - all-thread poll (no tid0+syncthreads convergence)
//  - per-wave release: own vmcnt(0) + lane0 fetch_add; threshold 20 = 5x4 waves
//  - no s_sleep in poll
// Keeps R9's safe improvements: waves_per_eu(1,1) for 512-VGPR residency,
// 3-deep x pipeline, y-duty split across waves 2/3, XCC_ID placement.

#define BATCH 1024
#define TT    120
#define HID   300
#define KX    160
#define KH    320   // 5 slices * 64
#define SL    64
#define HSL   60
#define NCOL  1280  // 5 slices * 256 packed gate columns
#define GH    5
#define GB    32
#define BS    32
#define XST   168   // x_lds row stride in shorts
#define FSTR  32    // flag stride in ints (128B)
#define NSLOT 3
#define NB    256
#define NREL  (GH * 4)   // releases per (t,bg): 5 slices x 4 waves

typedef __attribute__((ext_vector_type(8))) short bf16x8;
typedef __attribute__((ext_vector_type(4))) float f32x4;

__device__ __forceinline__ unsigned short f2b(float f) {
  union { float f; unsigned u; } v; v.f = f;
  unsigned r = v.u + 0x7fffu + ((v.u >> 16) & 1u);
  return (unsigned short)(r >> 16);
}
__device__ __forceinline__ float sigm(float x) {
  return __builtin_amdgcn_rcpf(1.f + __expf(-x));
}
__device__ __forceinline__ float tanhf_(float x) {
  return 2.f * __builtin_amdgcn_rcpf(1.f + __expf(-2.f * x)) - 1.f;
}

__global__ void k_reorder_wh(const float* __restrict__ W, unsigned short* __restrict__ Wp) {
  int tid = blockIdx.x * 256 + threadIdx.x;
  if (tid >= KH * NCOL) return;
  int c = tid % NCOL, k = tid / NCOL;
  int js = k >> 6, v0 = k & 63;
  int j = c >> 8, r = c & 255, g = r >> 6, u0 = r & 63;
  float val = 0.f;
  if (v0 < HSL && u0 < HSL) val = W[(js * HSL + v0) * 1200 + g * 300 + j * HSL + u0];
  Wp[((k >> 3) * NCOL + c) * 8 + (k & 7)] = f2b(val);
}

__global__ void k_reorder_wx(const float* __restrict__ W, unsigned short* __restrict__ Wp) {
  int tid = blockIdx.x * 256 + threadIdx.x;
  if (tid >= KX * NCOL) return;
  int c = tid % NCOL, k = tid / NCOL;
  int j = c >> 8, r = c & 255, g = r >> 6, u0 = r & 63;
  float val = 0.f;
  if (k < 150 && u0 < HSL) val = W[k * 1200 + g * 300 + j * HSL + u0];
  Wp[((k >> 3) * NCOL + c) * 8 + (k & 7)] = f2b(val);
}

__global__ void k_reorder_b(const float* __restrict__ b, float* __restrict__ bp) {
  int c = blockIdx.x * 256 + threadIdx.x;
  if (c >= NCOL) return;
  int j = c >> 8, r = c & 255, g = r >> 6, u0 = r & 63;
  bp[c] = (u0 < HSL) ? b[g * 300 + j * HSL + u0] : 0.f;
}

__global__ void k_reorder_u(const float* __restrict__ U, unsigned short* __restrict__ Up) {
  int tid = blockIdx.x * 256 + threadIdx.x;
  if (tid >= KH * 16) return;
  int n = tid % 16, k = tid / 16;
  int js = k >> 6, v0 = k & 63;
  float v = (v0 < HSL && n < 5) ? U[(js * HSL + v0) * 5 + n] : 0.f;
  Up[((k >> 3) * 16 + n) * 8 + (k & 7)] = f2b(v);
}

__launch_bounds__(256, 1)
__attribute__((amdgpu_waves_per_eu(1, 1)))
__global__ void k_lstm(const int* __restrict__ ids, const float* __restrict__ embed,
                       const unsigned short* __restrict__ Wp,
                       const unsigned short* __restrict__ Wxp,
                       const float* __restrict__ bp,
                       const unsigned short* __restrict__ Up,
                       unsigned short* __restrict__ hbuf,   // [3][1024][320] bf16
                       int* __restrict__ flags,             // [120][32] @128B counters
                       int* __restrict__ xcd_cnt,           // [8]
                       const float* __restrict__ b2,
                       float* __restrict__ out) {
  __shared__ __align__(16) unsigned short x_lds[2][BS * XST];
  __shared__ char lds_pad[61440];   // force 1 block/CU (total LDS > 80KB)
  __shared__ int role[2];

  const int tid = threadIdx.x;
  if (tid == 0) {
    ((volatile char*)lds_pad)[0] = 0;
    int xcd = __builtin_amdgcn_s_getreg(63508) & 7;  // HW_REG_XCC_ID
    int rank = atomicAdd(&xcd_cnt[xcd], 1);
    role[0] = xcd; role[1] = rank;
  }
  __syncthreads();
  const int xcd = role[0], rank = role[1];
  if (rank >= GH * 4) return;               // spare block
  const int bg = xcd * 4 + rank / GH;
  const int j  = rank % GH;

  const int lane = tid & 63, w = tid >> 6;
  const int l15 = lane & 15, l4 = lane >> 4;

  if (tid < BS) {
#pragma unroll
    for (int bq = 0; bq < 2; ++bq)
      for (int e = 150; e < XST; ++e) x_lds[bq][tid * XST + e] = 0;
  }

  const int colb = j * 256 + w * 16 + l15;

  bf16x8 bh[10][4], bx[5][4];
#pragma unroll
  for (int kk = 0; kk < 10; ++kk)
#pragma unroll
    for (int g = 0; g < 4; ++g)
      bh[kk][g] = *(const bf16x8*)(Wp + ((kk * 4 + l4) * NCOL + colb + g * 64) * 8);
#pragma unroll
  for (int kk = 0; kk < 5; ++kk)
#pragma unroll
    for (int g = 0; g < 4; ++g)
      bx[kk][g] = *(const bf16x8*)(Wxp + ((kk * 4 + l4) * NCOL + colb + g * 64) * 8);

  float bias[4];
#pragma unroll
  for (int g = 0; g < 4; ++g) bias[g] = bp[colb + g * 64];
  const float b2v = (l15 < 5) ? b2[l15] : 0.f;

  // gather geometry for tid<192
  int xrow = 0, koff = 0, nf2 = 0, f = 0;
  const bool gth = (tid < 192);
  if (gth) {
    xrow = tid / 6; int half = tid % 6; f = half >> 1; int hh = half & 1;
    nf2 = hh ? 12 : 13;
    koff = f * 50 + (hh ? 26 : 0);
  }
  const long idbase = (long)(bg * BS + xrow) * TT * 3 + f;
  const int  eoff   = (koff - f * 50);

  // ---- prologue: x(0) gather+pack, GEMM1(0), prime 3-deep pipeline
  if (gth) {
    int id0 = ids[idbase + 0 * 3];
    const float* src = embed + (long)id0 * 50 + eoff;
    unsigned short* dst = &x_lds[0][xrow * XST + koff];
#pragma unroll
    for (int e = 0; e < 13; ++e)
      if (e < nf2) {
        float2 v = *(const float2*)(src + 2 * e);
        *(unsigned*)(dst + 2 * e) = (unsigned)f2b(v.x) | ((unsigned)f2b(v.y) << 16);
      }
  }
  __syncthreads();

  f32x4 acc[4][2];
  float cst[2][4];
#pragma unroll
  for (int g = 0; g < 4; ++g)
#pragma unroll
    for (int mt = 0; mt < 2; ++mt) acc[g][mt] = {0.f, 0.f, 0.f, 0.f};
#pragma unroll
  for (int mt = 0; mt < 2; ++mt)
#pragma unroll
    for (int r = 0; r < 4; ++r) cst[mt][r] = 0.f;

  {
    const unsigned short* xb = &x_lds[0][l15 * XST + l4 * 8];
#pragma unroll
    for (int kk = 0; kk < 5; ++kk) {
      bf16x8 a0 = *(const bf16x8*)(xb + kk * 32);
      bf16x8 a1 = *(const bf16x8*)(xb + 16 * XST + kk * 32);
#pragma unroll
      for (int g = 0; g < 4; ++g) {
        acc[g][0] = __builtin_amdgcn_mfma_f32_16x16x32_bf16(a0, bx[kk][g], acc[g][0], 0, 0, 0);
        acc[g][1] = __builtin_amdgcn_mfma_f32_16x16x32_bf16(a1, bx[kk][g], acc[g][1], 0, 0, 0);
      }
    }
  }

  // pipeline regs: xv = embed(t+1) floats; idv = ids(t+2)
  float2 xv[13];
  int idv = 0;
  if (gth) {
    int id1 = ids[idbase + 1 * 3];
    const float* src = embed + (long)id1 * 50 + eoff;
#pragma unroll
    for (int e = 0; e < 13; ++e)
      if (e < nf2) xv[e] = *(const float2*)(src + 2 * e);
    idv = ids[idbase + 2 * 3];
  }

  bf16x8 va0[10], va1[10];

  for (int t = 0; t < TT; ++t) {
    if (t > 0) {
      // all-thread poll: R8-proven relaxed-AGENT atomic load (L1-bypassing)
      const int* fp = flags + ((t - 1) * GB + bg) * FSTR;
      int it = 0;
      while (__hip_atomic_load(fp, __ATOMIC_RELAXED, __HIP_MEMORY_SCOPE_AGENT) < NREL) {
        if (++it > 300000) break;  // bail -> wrong answer, not a hang
      }
      // per-wave: drop stale L1, then read partners' h from XCD L2 (R8-proven)
      asm volatile("buffer_inv\n\ts_waitcnt vmcnt(0)" ::: "memory");

      const unsigned short* ar =
          hbuf + ((t - 1) % NSLOT) * (BATCH * KH) + (bg * BS + l15) * KH + l4 * 8;
#pragma unroll
      for (int kk = 0; kk < 10; ++kk) {
        va0[kk] = *(const bf16x8*)(ar + kk * 32);
        va1[kk] = *(const bf16x8*)(ar + 16 * KH + kk * 32);
      }
#pragma unroll
      for (int kk = 0; kk < 10; ++kk) {
#pragma unroll
        for (int g = 0; g < 4; ++g) {
          acc[g][0] = __builtin_amdgcn_mfma_f32_16x16x32_bf16(va0[kk], bh[kk][g], acc[g][0], 0, 0, 0);
          acc[g][1] = __builtin_amdgcn_mfma_f32_16x16x32_bf16(va1[kk], bh[kk][g], acc[g][1], 0, 0, 0);
        }
      }
    }

    // gates + state update; h(t) packed 8B plain write-through stores -> local L2
    unsigned short* hdst = hbuf + (t % NSLOT) * (BATCH * KH);
#pragma unroll
    for (int mt = 0; mt < 2; ++mt) {
#pragma unroll
      for (int r = 0; r < 4; ++r) {
        float zi = acc[0][mt][r] + bias[0];
        float zf = acc[1][mt][r] + bias[1];
        float zg = acc[2][mt][r] + bias[2];
        float zo = acc[3][mt][r] + bias[3];
        float gi = sigm(zi), gf = sigm(zf), go = sigm(zo), gg = tanhf_(zg);
        float c = gf * cst[mt][r] + gi * gg;
        cst[mt][r] = c;
        float h = go * tanhf_(c);
        unsigned v = f2b(h);
        unsigned p1 = v | ((unsigned)__shfl_xor((int)v, 1) << 16);
        unsigned long long p2 = (unsigned long long)p1 |
            ((unsigned long long)(unsigned)__shfl_xor((int)p1, 2) << 32);
        if ((l15 & 3) == 0) {
          int row = bg * BS + mt * 16 + l4 * 4 + r;
          *(unsigned long long*)(hdst + row * KH + j * SL + w * 16 + l15) = p2;
        }
      }
      acc[0][mt] = {0.f, 0.f, 0.f, 0.f};
      acc[1][mt] = {0.f, 0.f, 0.f, 0.f};
      acc[2][mt] = {0.f, 0.f, 0.f, 0.f};
      acc[3][mt] = {0.f, 0.f, 0.f, 0.f};
    }

    // per-wave release: own stores L2-acked, then lane0 fetch_add (R8-proven op)
    asm volatile("s_waitcnt vmcnt(0)" ::: "memory");
    if ((tid & 63) == 0)
      __hip_atomic_fetch_add(flags + (t * GB + bg) * FSTR, 1, __ATOMIC_RELAXED,
                             __HIP_MEMORY_SCOPE_AGENT);

    // y(t-1) duty from register A-frags (waves 2/3; post-release, off chain)
    if (t > 0 && j == (t - 1) % GH) {
      if (w == 2) {
        f32x4 ay = {0.f, 0.f, 0.f, 0.f};
#pragma unroll
        for (int kk = 0; kk < 10; ++kk) {
          bf16x8 u = *(const bf16x8*)(Up + ((kk * 4 + l4) * 16 + l15) * 8);
          ay = __builtin_amdgcn_mfma_f32_16x16x32_bf16(va0[kk], u, ay, 0, 0, 0);
        }
        if (l15 < 5)
#pragma unroll
          for (int q = 0; q < 4; ++q)
            out[((bg * BS + l4 * 4 + q) * TT + (t - 1)) * 5 + l15] = ay[q] + b2v;
      } else if (w == 3) {
        f32x4 ay = {0.f, 0.f, 0.f, 0.f};
#pragma unroll
        for (int kk = 0; kk < 10; ++kk) {
          bf16x8 u = *(const bf16x8*)(Up + ((kk * 4 + l4) * 16 + l15) * 8);
          ay = __builtin_amdgcn_mfma_f32_16x16x32_bf16(va1[kk], u, ay, 0, 0, 0);
        }
        if (l15 < 5)
#pragma unroll
          for (int q = 0; q < 4; ++q)
            out[((bg * BS + 16 + l4 * 4 + q) * TT + (t - 1)) * 5 + l15] = ay[q] + b2v;
      }
    }

    // tail: pack x(t+1); GEMM1(t+1); refill pipeline (t+2 embed, t+3 ids)
    if (t + 1 < TT) {
      if (gth) {
        unsigned short* dst = &x_lds[(t + 1) & 1][xrow * XST + koff];
#pragma unroll
        for (int e = 0; e < 13; ++e)
          if (e < nf2)
            *(unsigned*)(dst + 2 * e) = (unsigned)f2b(xv[e].x) | ((unsigned)f2b(xv[e].y) << 16);
      }
      __syncthreads();
      const unsigned short* xb = &x_lds[(t + 1) & 1][l15 * XST + l4 * 8];
#pragma unroll
      for (int kk = 0; kk < 5; ++kk) {
        bf16x8 a0 = *(const bf16x8*)(xb + kk * 32);
        bf16x8 a1 = *(const bf16x8*)(xb + 16 * XST + kk * 32);
#pragma unroll
        for (int g = 0; g < 4; ++g) {
          acc[g][0] = __builtin_amdgcn_mfma_f32_16x16x32_bf16(a0, bx[kk][g], acc[g][0], 0, 0, 0);
          acc[g][1] = __builtin_amdgcn_mfma_f32_16x16x32_bf16(a1, bx[kk][g], acc[g][1], 0, 0, 0);
        }
      }
      if (gth && t + 2 < TT) {
        const float* src = embed + (long)idv * 50 + eoff;
#pragma unroll
        for (int e = 0; e < 13; ++e)
          if (e < nf2) xv[e] = *(const float2*)(src + 2 * e);
        if (t + 3 < TT) idv = ids[idbase + (long)(t + 3) * 3];
      }
    }
  }

  // epilogue: y(119) by slice 4
  if (j == (TT - 1) % GH) {
    const int* fp = flags + ((TT - 1) * GB + bg) * FSTR;
    int it = 0;
    while (__hip_atomic_load(fp, __ATOMIC_RELAXED, __HIP_MEMORY_SCOPE_AGENT) < NREL) {
      if (++it > 300000) break;
    }
    asm volatile("buffer_inv\n\ts_waitcnt vmcnt(0)" ::: "memory");
    const unsigned short* ar =
        hbuf + ((TT - 1) % NSLOT) * (BATCH * KH) + (bg * BS + l15) * KH + l4 * 8;
#pragma unroll
    for (int kk = 0; kk < 10; ++kk) {
      va0[kk] = *(const bf16x8*)(ar + kk * 32);
      va1[kk] = *(const bf16x8*)(ar + 16 * KH + kk * 32);
    }
    if (w == 2) {
      f32x4 ay = {0.f, 0.f, 0.f, 0.f};
#pragma unroll
      for (int kk = 0; kk < 10; ++kk) {
        bf16x8 u = *(const bf16x8*)(Up + ((kk * 4 + l4) * 16 + l15) * 8);
        ay = __builtin_amdgcn_mfma_f32_16x16x32_bf16(va0[kk], u, ay, 0, 0, 0);
      }
      if (l15 < 5)
#pragma unroll
        for (int q = 0; q < 4; ++q)
          out[((bg * BS + l4 * 4 + q) * TT + (TT - 1)) * 5 + l15] = ay[q] + b2v;
    } else if (w == 3) {
      f32x4 ay = {0.f, 0.f, 0.f, 0.f};
#pragma unroll
      for (int kk = 0; kk < 10; ++kk) {
        bf16x8 u = *(const bf16x8*)(Up + ((kk * 4 + l4) * 16 + l15) * 8);
        ay = __builtin_amdgcn_mfma_f32_16x16x32_bf16(va1[kk], u, ay, 0, 0, 0);
      }
      if (l15 < 5)
#pragma unroll
        for (int q = 0; q < 4; ++q)
          out[((bg * BS + 16 + l4 * 4 + q) * TT + (TT - 1)) * 5 + l15] = ay[q] + b2v;
    }
  }
}

extern "C" void kernel_launch(void* const* d_in, const int* in_sizes, int n_in,
                              void* d_out, int out_size, void* d_ws, size_t ws_size,
                              hipStream_t stream) {
  const int*   ids   = (const int*)d_in[0];
  const float* embed = (const float*)d_in[1];
  const float* Wx    = (const float*)d_in[2];
  const float* Wh    = (const float*)d_in[3];
  const float* b     = (const float*)d_in[4];
  const float* U     = (const float*)d_in[5];
  const float* b2    = (const float*)d_in[6];
  float* out = (float*)d_out;

  char* ws = (char*)d_ws;
  size_t off = 0;
  unsigned short* Wp   = (unsigned short*)(ws + off); off += (size_t)KH * NCOL * 2;
  unsigned short* Wxp  = (unsigned short*)(ws + off); off += (size_t)KX * NCOL * 2;
  float*          bp   = (float*)(ws + off);          off += (size_t)NCOL * 4;
  unsigned short* Up   = (unsigned short*)(ws + off); off += (size_t)KH * 16 * 2;
  unsigned short* hbuf = (unsigned short*)(ws + off); off += (size_t)NSLOT * BATCH * KH * 2;
  int*            flags= (int*)(ws + off);            off += (size_t)TT * GB * FSTR * 4;
  int*            xcd_cnt = (int*)(ws + off);         off += 8 * 4;
  if (ws_size < off) return;  // ~3.7 MB required

  hipMemsetAsync(flags, 0, TT * GB * FSTR * 4 + 8 * 4, stream);  // flags + xcd_cnt
  k_reorder_wh<<<(KH * NCOL + 255) / 256, 256, 0, stream>>>(Wh, Wp);
  k_reorder_wx<<<(KX * NCOL + 255) / 256, 256, 0, stream>>>(Wx, Wxp);
  k_reorder_b<<<(NCOL + 255) / 256, 256, 0, stream>>>(b, bp);
  k_reorder_u<<<(KH * 16 + 255) / 256, 256, 0, stream>>>(U, Up);

  k_lstm<<<dim3(NB), dim3(256), 0, stream>>>(ids, embed, Wp, Wxp, bp, Up,
                                             hbuf, flags, xcd_cnt, b2, out);
}